// Round 2
// baseline (179.639 us; speedup 1.0000x reference)
//
#include <hip/hip_runtime.h>
#include <hip/hip_bf16.h>

// WaveletBlock fused kernel (f32 in/out): DWT -> GEMM1(+bias,SiLU) -> GEMM2(+bias) -> IDWT
// One workgroup (256 threads = 4 waves) per (image n, DWT row hh):
//   64 pixels (ww) x 256 channels, K=256 both GEMMs, intermediates in LDS as bf16.

typedef __bf16 bf16x8 __attribute__((ext_vector_type(8)));
typedef float  f32x4  __attribute__((ext_vector_type(4)));

#define SP 264  // LDS row stride in bf16 elems: 528 B = 132 dwords == 4 mod 32 banks
                // -> row-strided lane access is <=2-way (free); rows stay 16B-aligned.

__device__ __forceinline__ unsigned short f2bf(float f) {
  __hip_bfloat16 h = __float2bfloat16(f);
  return __builtin_bit_cast(unsigned short, h);
}
__device__ __forceinline__ float bf2f(unsigned short s) {
  union { unsigned int i; float f; } v; v.i = ((unsigned int)s) << 16; return v.f;
}
__device__ __forceinline__ float silu(float f) {
  return f / (1.0f + __expf(-f));
}
// Load 8 consecutive f32 weights, convert to a bf16x8 MFMA fragment.
__device__ __forceinline__ bf16x8 ldw8(const float* __restrict__ p) {
  const float4 a = *(const float4*)p;
  const float4 b = *(const float4*)(p + 4);
  bf16x8 r;
  r[0] = (__bf16)a.x; r[1] = (__bf16)a.y; r[2] = (__bf16)a.z; r[3] = (__bf16)a.w;
  r[4] = (__bf16)b.x; r[5] = (__bf16)b.y; r[6] = (__bf16)b.z; r[7] = (__bf16)b.w;
  return r;
}

__global__ __launch_bounds__(256, 2)
void wavelet_fused(const float* __restrict__ x,
                   const float* __restrict__ w1,
                   const float* __restrict__ b1,
                   const float* __restrict__ w2,
                   const float* __restrict__ b2,
                   float* __restrict__ out)
{
  // ldsA: x_dwt tile [pixel][c4] (phases 1-2), then y tile [pixel][c4] (phases 3-4).
  // ldsB: feat tile [pixel][o] between GEMM1 and GEMM2.
  __shared__ unsigned short ldsA[64 * SP];
  __shared__ unsigned short ldsB[64 * SP];

  const int t  = threadIdx.x;
  const int n  = blockIdx.x >> 6;   // image (b*8+l)
  const int hh = blockIdx.x & 63;   // DWT row

  const int ww = t & 63;            // pixel column for phases 1/4 (lane-contiguous -> coalesced)
  const int cg = t >> 6;

  // ---------------- Phase 1: Haar DWT -> ldsA[ww][q*64+c] ----------------
  {
    const float* xb = x + ((size_t)n * 64 * 128 + (size_t)(2 * hh)) * 128 + 2 * ww;
    #pragma unroll
    for (int j = 0; j < 4; ++j) {
      const int c0 = (cg + 4 * j) * 4;
      float qv[4][4];
      #pragma unroll
      for (int ci = 0; ci < 4; ++ci) {
        const float* p = xb + (size_t)(c0 + ci) * (128 * 128);
        const float2 r0 = *(const float2*)p;          // x[2hh,   2ww], x[2hh,   2ww+1]
        const float2 r1 = *(const float2*)(p + 128);  // x[2hh+1, 2ww], x[2hh+1, 2ww+1]
        const float x1 = r0.x, x3 = r0.y;             // even row: even col, odd col
        const float x2 = r1.x, x4 = r1.y;             // odd  row: even col, odd col
        qv[0][ci] = 0.5f * ((x1 + x2) + (x3 + x4));
        qv[1][ci] = 0.5f * ((x3 + x4) - (x1 + x2));
        qv[2][ci] = 0.5f * ((x2 + x4) - (x1 + x3));
        qv[3][ci] = 0.5f * ((x1 + x4) - (x2 + x3));
      }
      #pragma unroll
      for (int q = 0; q < 4; ++q) {
        ushort4 v = make_ushort4(f2bf(qv[q][0]), f2bf(qv[q][1]), f2bf(qv[q][2]), f2bf(qv[q][3]));
        *(ushort4*)(&ldsA[ww * SP + q * 64 + c0]) = v;  // b64 write, 4 consecutive c at fixed q
      }
    }
  }
  __syncthreads();

  const int wv   = t >> 6;        // wave id: o-slice / c4-slice of 64 rows
  const int r    = t & 15;        // MFMA row/col-in-tile
  const int quad = (t & 63) >> 4; // MFMA quad: k-offset (inputs) / row-offset (output)

  // ---------------- Phase 2: GEMM1  D[o][pix] = conv_w . x_dwt;  silu -> ldsB[pix][o] ----------------
  {
    f32x4 acc[4][4];
    #pragma unroll
    for (int mt = 0; mt < 4; ++mt)
      #pragma unroll
      for (int nt = 0; nt < 4; ++nt)
        acc[mt][nt] = (f32x4){0.0f, 0.0f, 0.0f, 0.0f};

    const float* wA = w1 + (wv * 64 + r) * 256 + quad * 8;
    #pragma unroll
    for (int k0 = 0; k0 < 256; k0 += 32) {
      bf16x8 a[4], b[4];
      #pragma unroll
      for (int mt = 0; mt < 4; ++mt)   // A: conv_w rows o (f32 from L2 -> bf16)
        a[mt] = ldw8(wA + mt * (16 * 256) + k0);
      #pragma unroll
      for (int nt = 0; nt < 4; ++nt)   // B: x_dwt[pix][k] (ds_read_b128)
        b[nt] = *(const bf16x8*)(&ldsA[(nt * 16 + r) * SP + quad * 8 + k0]);
      #pragma unroll
      for (int mt = 0; mt < 4; ++mt)
        #pragma unroll
        for (int nt = 0; nt < 4; ++nt)
          acc[mt][nt] = __builtin_amdgcn_mfma_f32_16x16x32_bf16(a[mt], b[nt], acc[mt][nt], 0, 0, 0);
    }

    // Epilogue: lane holds 4 consecutive o (rows) at col pix -> b64 LDS write
    #pragma unroll
    for (int mt = 0; mt < 4; ++mt) {
      const int ob = wv * 64 + mt * 16 + quad * 4;
      const float4 bb = *(const float4*)(b1 + ob);
      #pragma unroll
      for (int nt = 0; nt < 4; ++nt) {
        const int pix = nt * 16 + r;
        ushort4 v;
        v.x = f2bf(silu(acc[mt][nt][0] + bb.x));
        v.y = f2bf(silu(acc[mt][nt][1] + bb.y));
        v.z = f2bf(silu(acc[mt][nt][2] + bb.z));
        v.w = f2bf(silu(acc[mt][nt][3] + bb.w));
        *(ushort4*)(&ldsB[pix * SP + ob]) = v;
      }
    }
  }
  __syncthreads();

  // ---------------- Phase 3: GEMM2  D[c4][pix] = conv_out_w . feat -> ldsA[pix][c4] ----------------
  {
    f32x4 acc[4][4];
    #pragma unroll
    for (int mt = 0; mt < 4; ++mt)
      #pragma unroll
      for (int nt = 0; nt < 4; ++nt)
        acc[mt][nt] = (f32x4){0.0f, 0.0f, 0.0f, 0.0f};

    const float* wA = w2 + (wv * 64 + r) * 256 + quad * 8;
    #pragma unroll
    for (int k0 = 0; k0 < 256; k0 += 32) {
      bf16x8 a[4], b[4];
      #pragma unroll
      for (int mt = 0; mt < 4; ++mt)   // A: conv_out_w rows c4 (f32 from L2 -> bf16)
        a[mt] = ldw8(wA + mt * (16 * 256) + k0);
      #pragma unroll
      for (int nt = 0; nt < 4; ++nt)   // B: feat[pix][o]
        b[nt] = *(const bf16x8*)(&ldsB[(nt * 16 + r) * SP + quad * 8 + k0]);
      #pragma unroll
      for (int mt = 0; mt < 4; ++mt)
        #pragma unroll
        for (int nt = 0; nt < 4; ++nt)
          acc[mt][nt] = __builtin_amdgcn_mfma_f32_16x16x32_bf16(a[mt], b[nt], acc[mt][nt], 0, 0, 0);
    }

    #pragma unroll
    for (int mt = 0; mt < 4; ++mt) {
      const int cb = wv * 64 + mt * 16 + quad * 4;
      const float4 bb = *(const float4*)(b2 + cb);
      #pragma unroll
      for (int nt = 0; nt < 4; ++nt) {
        const int pix = nt * 16 + r;
        ushort4 v;
        v.x = f2bf(acc[mt][nt][0] + bb.x);
        v.y = f2bf(acc[mt][nt][1] + bb.y);
        v.z = f2bf(acc[mt][nt][2] + bb.z);
        v.w = f2bf(acc[mt][nt][3] + bb.w);
        *(ushort4*)(&ldsA[pix * SP + cb]) = v;
      }
    }
  }
  __syncthreads();

  // ---------------- Phase 4: IDWT + coalesced float2 stores ----------------
  {
    float* ob_ = out + ((size_t)n * 64 * 128 + (size_t)(2 * hh)) * 128 + 2 * ww;
    #pragma unroll
    for (int j = 0; j < 4; ++j) {
      const int c0 = (cg + 4 * j) * 4;
      unsigned short yb[4][4];
      #pragma unroll
      for (int q = 0; q < 4; ++q) {
        const ushort4 v = *(const ushort4*)(&ldsA[ww * SP + q * 64 + c0]);
        yb[q][0] = v.x; yb[q][1] = v.y; yb[q][2] = v.z; yb[q][3] = v.w;
      }
      #pragma unroll
      for (int ci = 0; ci < 4; ++ci) {
        const float y1 = 0.5f * bf2f(yb[0][ci]);
        const float y2 = 0.5f * bf2f(yb[1][ci]);
        const float y3 = 0.5f * bf2f(yb[2][ci]);
        const float y4 = 0.5f * bf2f(yb[3][ci]);
        const float s14 = y1 + y4, s23 = y2 + y3;
        const float d14 = y1 - y4, d23 = y2 - y3;
        const float oa  = s14 - s23;  // (2hh,   2ww)
        const float oc  = d14 + d23;  // (2hh,   2ww+1)
        const float obv = d14 - d23;  // (2hh+1, 2ww)
        const float od  = s14 + s23;  // (2hh+1, 2ww+1)
        float* prow = ob_ + (size_t)(c0 + ci) * (128 * 128);
        *(float2*)prow         = make_float2(oa, oc);
        *(float2*)(prow + 128) = make_float2(obv, od);
      }
    }
  }
}

extern "C" void kernel_launch(void* const* d_in, const int* in_sizes, int n_in,
                              void* d_out, int out_size, void* d_ws, size_t ws_size,
                              hipStream_t stream) {
  (void)in_sizes; (void)n_in; (void)out_size; (void)d_ws; (void)ws_size;
  const float* x  = (const float*)d_in[0];
  const float* w1 = (const float*)d_in[1];
  const float* b1 = (const float*)d_in[2];
  const float* w2 = (const float*)d_in[3];
  const float* b2 = (const float*)d_in[4];
  float* o = (float*)d_out;
  // grid: 16 images x 64 DWT rows
  wavelet_fused<<<dim3(16 * 64), dim3(256), 0, stream>>>(x, w1, b1, w2, b2, o);
}

// Round 3
// 154.846 us; speedup vs baseline: 1.1601x; 1.1601x over previous
//
#include <hip/hip_runtime.h>
#include <hip/hip_bf16.h>

// WaveletBlock fused kernel (f32 in/out): DWT -> GEMM1(+bias,SiLU) -> GEMM2(+bias) -> IDWT
// One workgroup (256 threads = 4 waves) per (image n, DWT row hh):
//   64 pixels (ww) x 256 channels, K=256 both GEMMs.
// R3: single 33.8 KB LDS buffer (x_dwt -> feat -> y, barrier-separated) => 4 blocks/CU,
//     all 1024 blocks co-resident in one generation. Weights pre-converted to bf16 in
//     d_ws by a prelude kernel (half fetch bytes, no cvt in hot loop).

typedef __bf16 bf16x8 __attribute__((ext_vector_type(8)));
typedef float  f32x4  __attribute__((ext_vector_type(4)));

#define SP 264  // LDS row stride in bf16 elems: 528 B = 132 dwords == 4 mod 32 banks;
                // rows stay 16B-aligned for ds_read_b128. GEMM-phase accesses are <=2-way.

__device__ __forceinline__ unsigned short f2bf(float f) {
  __hip_bfloat16 h = __float2bfloat16(f);
  return __builtin_bit_cast(unsigned short, h);
}
__device__ __forceinline__ float bf2f(unsigned short s) {
  union { unsigned int i; float f; } v; v.i = ((unsigned int)s) << 16; return v.f;
}
__device__ __forceinline__ float silu(float f) {
  return f / (1.0f + __expf(-f));
}
// Load 8 consecutive f32 weights, convert to a bf16x8 MFMA fragment (fallback path).
__device__ __forceinline__ bf16x8 ldw8(const float* __restrict__ p) {
  const float4 a = *(const float4*)p;
  const float4 b = *(const float4*)(p + 4);
  bf16x8 r;
  r[0] = (__bf16)a.x; r[1] = (__bf16)a.y; r[2] = (__bf16)a.z; r[3] = (__bf16)a.w;
  r[4] = (__bf16)b.x; r[5] = (__bf16)b.y; r[6] = (__bf16)b.z; r[7] = (__bf16)b.w;
  return r;
}

// Prelude: f32 -> bf16 weight conversion into workspace (runs every call; d_ws is re-poisoned).
__global__ __launch_bounds__(256) void cvt_w(const float* __restrict__ w1,
                                             const float* __restrict__ w2,
                                             unsigned short* __restrict__ o) {
  const int i = (blockIdx.x * 256 + threadIdx.x) * 4;  // grid 64 x 256 covers 65536
  const float4 a = *(const float4*)(w1 + i);
  const float4 b = *(const float4*)(w2 + i);
  *(ushort4*)(o + i)         = make_ushort4(f2bf(a.x), f2bf(a.y), f2bf(a.z), f2bf(a.w));
  *(ushort4*)(o + 65536 + i) = make_ushort4(f2bf(b.x), f2bf(b.y), f2bf(b.z), f2bf(b.w));
}

template <bool WBF16>
__global__ __launch_bounds__(256, 4)
void wavelet_fused(const float* __restrict__ x,
                   const void* __restrict__ w1p,
                   const float* __restrict__ b1,
                   const void* __restrict__ w2p,
                   const float* __restrict__ b2,
                   float* __restrict__ out)
{
  // One buffer, three lives: x_dwt [pix][c4] -> feat [pix][o] -> y [pix][c4].
  __shared__ unsigned short lds[64 * SP];  // 33,792 B => 4 blocks/CU on 160 KiB

  const int t  = threadIdx.x;
  const int n  = blockIdx.x >> 6;   // image (b*8+l)
  const int hh = blockIdx.x & 63;   // DWT row

  const int ww = t & 63;            // pixel column for phases 1/4 (lane-contiguous -> coalesced)
  const int cg = t >> 6;

  // ---------------- Phase 1: Haar DWT -> lds[ww][q*64+c] ----------------
  {
    const float* xb = x + ((size_t)n * 64 * 128 + (size_t)(2 * hh)) * 128 + 2 * ww;
    #pragma unroll
    for (int j = 0; j < 4; ++j) {
      const int c0 = (cg + 4 * j) * 4;
      float qv[4][4];
      #pragma unroll
      for (int ci = 0; ci < 4; ++ci) {
        const float* p = xb + (size_t)(c0 + ci) * (128 * 128);
        const float2 r0 = *(const float2*)p;          // x[2hh,   2ww], x[2hh,   2ww+1]
        const float2 r1 = *(const float2*)(p + 128);  // x[2hh+1, 2ww], x[2hh+1, 2ww+1]
        const float x1 = r0.x, x3 = r0.y;             // even row: even col, odd col
        const float x2 = r1.x, x4 = r1.y;             // odd  row: even col, odd col
        qv[0][ci] = 0.5f * ((x1 + x2) + (x3 + x4));
        qv[1][ci] = 0.5f * ((x3 + x4) - (x1 + x2));
        qv[2][ci] = 0.5f * ((x2 + x4) - (x1 + x3));
        qv[3][ci] = 0.5f * ((x1 + x4) - (x2 + x3));
      }
      #pragma unroll
      for (int q = 0; q < 4; ++q) {
        ushort4 v = make_ushort4(f2bf(qv[q][0]), f2bf(qv[q][1]), f2bf(qv[q][2]), f2bf(qv[q][3]));
        *(ushort4*)(&lds[ww * SP + q * 64 + c0]) = v;
      }
    }
  }
  __syncthreads();

  const int wv   = t >> 6;        // wave id: o-slice / c4-slice of 64 rows
  const int r    = t & 15;        // MFMA row/col-in-tile
  const int quad = (t & 63) >> 4; // MFMA quad: k-offset (inputs) / row-offset (output)

  // ---------------- Phase 2: GEMM1  D[o][pix] = conv_w . x_dwt;  silu -> lds[pix][o] ----------------
  {
    f32x4 acc[4][4];
    #pragma unroll
    for (int mt = 0; mt < 4; ++mt)
      #pragma unroll
      for (int nt = 0; nt < 4; ++nt)
        acc[mt][nt] = (f32x4){0.0f, 0.0f, 0.0f, 0.0f};

    #pragma unroll
    for (int k0 = 0; k0 < 256; k0 += 32) {
      bf16x8 a[4], b[4];
      #pragma unroll
      for (int mt = 0; mt < 4; ++mt) {  // A: conv_w rows o (L2-resident)
        const int row = wv * 64 + mt * 16 + r;
        if constexpr (WBF16)
          a[mt] = *(const bf16x8*)((const unsigned short*)w1p + row * 256 + quad * 8 + k0);
        else
          a[mt] = ldw8((const float*)w1p + row * 256 + quad * 8 + k0);
      }
      #pragma unroll
      for (int nt = 0; nt < 4; ++nt)   // B: x_dwt[pix][k] (ds_read_b128)
        b[nt] = *(const bf16x8*)(&lds[(nt * 16 + r) * SP + quad * 8 + k0]);
      #pragma unroll
      for (int mt = 0; mt < 4; ++mt)
        #pragma unroll
        for (int nt = 0; nt < 4; ++nt)
          acc[mt][nt] = __builtin_amdgcn_mfma_f32_16x16x32_bf16(a[mt], b[nt], acc[mt][nt], 0, 0, 0);
    }
    __syncthreads();  // all GEMM1 reads of lds done

    // Epilogue: lane holds 4 consecutive o (rows) at col pix -> b64 LDS write
    #pragma unroll
    for (int mt = 0; mt < 4; ++mt) {
      const int ob = wv * 64 + mt * 16 + quad * 4;
      const float4 bb = *(const float4*)(b1 + ob);
      #pragma unroll
      for (int nt = 0; nt < 4; ++nt) {
        const int pix = nt * 16 + r;
        ushort4 v;
        v.x = f2bf(silu(acc[mt][nt][0] + bb.x));
        v.y = f2bf(silu(acc[mt][nt][1] + bb.y));
        v.z = f2bf(silu(acc[mt][nt][2] + bb.z));
        v.w = f2bf(silu(acc[mt][nt][3] + bb.w));
        *(ushort4*)(&lds[pix * SP + ob]) = v;
      }
    }
  }
  __syncthreads();

  // ---------------- Phase 3: GEMM2  D[c4][pix] = conv_out_w . feat -> lds[pix][c4] ----------------
  {
    f32x4 acc[4][4];
    #pragma unroll
    for (int mt = 0; mt < 4; ++mt)
      #pragma unroll
      for (int nt = 0; nt < 4; ++nt)
        acc[mt][nt] = (f32x4){0.0f, 0.0f, 0.0f, 0.0f};

    #pragma unroll
    for (int k0 = 0; k0 < 256; k0 += 32) {
      bf16x8 a[4], b[4];
      #pragma unroll
      for (int mt = 0; mt < 4; ++mt) {  // A: conv_out_w rows c4
        const int row = wv * 64 + mt * 16 + r;
        if constexpr (WBF16)
          a[mt] = *(const bf16x8*)((const unsigned short*)w2p + row * 256 + quad * 8 + k0);
        else
          a[mt] = ldw8((const float*)w2p + row * 256 + quad * 8 + k0);
      }
      #pragma unroll
      for (int nt = 0; nt < 4; ++nt)   // B: feat[pix][o]
        b[nt] = *(const bf16x8*)(&lds[(nt * 16 + r) * SP + quad * 8 + k0]);
      #pragma unroll
      for (int mt = 0; mt < 4; ++mt)
        #pragma unroll
        for (int nt = 0; nt < 4; ++nt)
          acc[mt][nt] = __builtin_amdgcn_mfma_f32_16x16x32_bf16(a[mt], b[nt], acc[mt][nt], 0, 0, 0);
    }
    __syncthreads();  // all GEMM2 reads of lds done

    #pragma unroll
    for (int mt = 0; mt < 4; ++mt) {
      const int cb = wv * 64 + mt * 16 + quad * 4;
      const float4 bb = *(const float4*)(b2 + cb);
      #pragma unroll
      for (int nt = 0; nt < 4; ++nt) {
        const int pix = nt * 16 + r;
        ushort4 v;
        v.x = f2bf(acc[mt][nt][0] + bb.x);
        v.y = f2bf(acc[mt][nt][1] + bb.y);
        v.z = f2bf(acc[mt][nt][2] + bb.z);
        v.w = f2bf(acc[mt][nt][3] + bb.w);
        *(ushort4*)(&lds[pix * SP + cb]) = v;
      }
    }
  }
  __syncthreads();

  // ---------------- Phase 4: IDWT + coalesced float2 stores ----------------
  {
    float* ob_ = out + ((size_t)n * 64 * 128 + (size_t)(2 * hh)) * 128 + 2 * ww;
    #pragma unroll
    for (int j = 0; j < 4; ++j) {
      const int c0 = (cg + 4 * j) * 4;
      unsigned short yb[4][4];
      #pragma unroll
      for (int q = 0; q < 4; ++q) {
        const ushort4 v = *(const ushort4*)(&lds[ww * SP + q * 64 + c0]);
        yb[q][0] = v.x; yb[q][1] = v.y; yb[q][2] = v.z; yb[q][3] = v.w;
      }
      #pragma unroll
      for (int ci = 0; ci < 4; ++ci) {
        const float y1 = 0.5f * bf2f(yb[0][ci]);
        const float y2 = 0.5f * bf2f(yb[1][ci]);
        const float y3 = 0.5f * bf2f(yb[2][ci]);
        const float y4 = 0.5f * bf2f(yb[3][ci]);
        const float s14 = y1 + y4, s23 = y2 + y3;
        const float d14 = y1 - y4, d23 = y2 - y3;
        const float oa  = s14 - s23;  // (2hh,   2ww)
        const float oc  = d14 + d23;  // (2hh,   2ww+1)
        const float obv = d14 - d23;  // (2hh+1, 2ww)
        const float od  = s14 + s23;  // (2hh+1, 2ww+1)
        float* prow = ob_ + (size_t)(c0 + ci) * (128 * 128);
        *(float2*)prow         = make_float2(oa, oc);
        *(float2*)(prow + 128) = make_float2(obv, od);
      }
    }
  }
}

extern "C" void kernel_launch(void* const* d_in, const int* in_sizes, int n_in,
                              void* d_out, int out_size, void* d_ws, size_t ws_size,
                              hipStream_t stream) {
  (void)in_sizes; (void)n_in; (void)out_size;
  const float* x  = (const float*)d_in[0];
  const float* w1 = (const float*)d_in[1];
  const float* b1 = (const float*)d_in[2];
  const float* w2 = (const float*)d_in[3];
  const float* b2 = (const float*)d_in[4];
  float* o = (float*)d_out;

  if (ws_size >= 2u * 65536u * sizeof(unsigned short)) {
    unsigned short* wb = (unsigned short*)d_ws;
    cvt_w<<<dim3(64), dim3(256), 0, stream>>>(w1, w2, wb);
    wavelet_fused<true><<<dim3(16 * 64), dim3(256), 0, stream>>>(
        x, wb, b1, wb + 65536, b2, o);
  } else {
    wavelet_fused<false><<<dim3(16 * 64), dim3(256), 0, stream>>>(
        x, w1, b1, w2, b2, o);
  }
}